// Round 1
// baseline (1325.933 us; speedup 1.0000x reference)
//
#include <hip/hip_runtime.h>

#define N_NODES 150000
#define N_EDGES 2400000
#define D 32

// ---------- degree / normalization ----------
__global__ void k_set1(float* __restrict__ p, int n) {
    int i = blockIdx.x * blockDim.x + threadIdx.x;
    if (i < n) p[i] = 1.0f;  // self-loop contributes 1 to every degree
}

__global__ void k_count(const int* __restrict__ dst, float* __restrict__ deg, int e) {
    int i = blockIdx.x * blockDim.x + threadIdx.x;
    if (i < e) atomicAdd(&deg[dst[i]], 1.0f);
}

__global__ void k_rsqrt(float* __restrict__ p, int n) {
    int i = blockIdx.x * blockDim.x + threadIdx.x;
    if (i < n) p[i] = rsqrtf(p[i]);
}

// ---------- fc1: [N,2] @ [2,32] + b, relu ----------
__global__ void k_fc1(const float* __restrict__ x, const float* __restrict__ w,
                      const float* __restrict__ b, float* __restrict__ h) {
    int t = blockIdx.x * blockDim.x + threadIdx.x;
    if (t >= N_NODES * D) return;
    int i = t >> 5, f = t & 31;
    float v = fmaf(x[2 * i], w[f], fmaf(x[2 * i + 1], w[D + f], b[f]));
    h[t] = v > 0.f ? v : 0.f;
}

// ---------- hw[i][f] = dis[i] * sum_k h[i][k]*W[k][f]; acc init with self-loop term ----------
__global__ __launch_bounds__(256) void k_transform(const float* __restrict__ h,
                                                   const float* __restrict__ W,
                                                   const float* __restrict__ dis,
                                                   float* __restrict__ hw,
                                                   float* __restrict__ acc) {
    __shared__ float Ws[D * D];
    int lt = threadIdx.x;
    for (int k = lt; k < D * D; k += 256) Ws[k] = W[k];
    __syncthreads();
    int t = blockIdx.x * 256 + lt;
    int i = t >> 5, f = t & 31;
    if (i >= N_NODES) return;
    float hv = h[i * D + f];
    float a = 0.f;
#pragma unroll
    for (int k = 0; k < D; ++k) {
        float hk = __shfl(hv, k, 32);          // broadcast h[i][k] within 32-lane group
        a = fmaf(hk, Ws[k * D + f], a);
    }
    a *= dis[i];
    hw[i * D + f] = a;
    acc[i * D + f] = a;  // self-loop: out[d] gets hw[d]*dis[d]; dis[d] applied at finalize
}

// ---------- scatter: acc[d] += hw[s]  (norm dis[s] folded into hw, dis[d] at finalize) ----------
__global__ __launch_bounds__(256) void k_scatter(const int* __restrict__ src,
                                                 const int* __restrict__ dst,
                                                 const float* __restrict__ hw,
                                                 float* __restrict__ acc) {
    int t = blockIdx.x * 256 + threadIdx.x;
    int e = t >> 5, f = t & 31;
    if (e >= N_EDGES) return;
    int s = src[e], d = dst[e];
    atomicAdd(&acc[d * D + f], hw[s * D + f]);
}

// ---------- finalize into next-layer h: relu(acc*dis + b) ----------
__global__ void k_fin_h(const float* __restrict__ acc, const float* __restrict__ dis,
                        const float* __restrict__ b, float* __restrict__ h) {
    int t = blockIdx.x * blockDim.x + threadIdx.x;
    if (t >= N_NODES * D) return;
    int i = t >> 5, f = t & 31;
    float v = fmaf(acc[t], dis[i], b[f]);
    h[t] = v > 0.f ? v : 0.f;
}

// ---------- finalize head: x = relu(acc*dis + cb) @ fw + fb -> out[:, col] ----------
__global__ void k_fin_out(const float* __restrict__ acc, const float* __restrict__ dis,
                          const float* __restrict__ cb, const float* __restrict__ fw,
                          const float* __restrict__ fb, float* __restrict__ out, int col) {
    int t = blockIdx.x * blockDim.x + threadIdx.x;
    int i = t >> 5, f = t & 31;
    if (i >= N_NODES) return;
    float v = fmaf(acc[t], dis[i], cb[f]);
    v = v > 0.f ? v : 0.f;
    v *= fw[f];
#pragma unroll
    for (int o = 16; o > 0; o >>= 1) v += __shfl_down(v, o, 32);
    if (f == 0) out[i * 2 + col] = v + fb[0];
}

extern "C" void kernel_launch(void* const* d_in, const int* in_sizes, int n_in,
                              void* d_out, int out_size, void* d_ws, size_t ws_size,
                              hipStream_t stream) {
    const float* x       = (const float*)d_in[0];
    const int*   eidx    = (const int*)d_in[1];
    const float* fc1_w   = (const float*)d_in[2];
    const float* fc1_b   = (const float*)d_in[3];
    const float* conv1_w = (const float*)d_in[4];
    const float* conv1_b = (const float*)d_in[5];
    const float* conv2_w = (const float*)d_in[6];
    const float* conv2_b = (const float*)d_in[7];
    const float* c31_w   = (const float*)d_in[8];
    const float* c31_b   = (const float*)d_in[9];
    const float* c32_w   = (const float*)d_in[10];
    const float* c32_b   = (const float*)d_in[11];
    const float* fc21_w  = (const float*)d_in[12];
    const float* fc21_b  = (const float*)d_in[13];
    const float* fc22_w  = (const float*)d_in[14];
    const float* fc22_b  = (const float*)d_in[15];
    float* out = (float*)d_out;

    const int* src = eidx;            // edge_index[0]
    const int* dst = eidx + N_EDGES;  // edge_index[1]

    float* ws  = (float*)d_ws;
    float* dis = ws;                    // N
    float* A   = ws + N_NODES;          // N*D
    float* B   = A + N_NODES * D;       // N*D (hw)
    float* C   = B + N_NODES * D;       // N*D (acc)

    const int BLK = 256;
    const int gN   = (N_NODES + BLK - 1) / BLK;
    const int gND  = (N_NODES * D + BLK - 1) / BLK;
    const int gE   = (N_EDGES + BLK - 1) / BLK;
    const int gE32 = (N_EDGES * 32 + BLK - 1) / BLK;

    // normalization coefficients (layer-invariant)
    k_set1<<<gN, BLK, 0, stream>>>(dis, N_NODES);
    k_count<<<gE, BLK, 0, stream>>>(dst, dis, N_EDGES);
    k_rsqrt<<<gN, BLK, 0, stream>>>(dis, N_NODES);

    // h0 = relu(x @ fc1_w + fc1_b) -> A
    k_fc1<<<gND, BLK, 0, stream>>>(x, fc1_w, fc1_b, A);

    // conv1: A -> (B=hw, C=acc) -> scatter -> h1 in A
    k_transform<<<gND, BLK, 0, stream>>>(A, conv1_w, dis, B, C);
    k_scatter<<<gE32, BLK, 0, stream>>>(src, dst, B, C);
    k_fin_h<<<gND, BLK, 0, stream>>>(C, dis, conv1_b, A);

    // conv2: A -> (B, C) -> scatter -> h2 in A
    k_transform<<<gND, BLK, 0, stream>>>(A, conv2_w, dis, B, C);
    k_scatter<<<gE32, BLK, 0, stream>>>(src, dst, B, C);
    k_fin_h<<<gND, BLK, 0, stream>>>(C, dis, conv2_b, A);

    // conv31 head -> out[:,0]
    k_transform<<<gND, BLK, 0, stream>>>(A, c31_w, dis, B, C);
    k_scatter<<<gE32, BLK, 0, stream>>>(src, dst, B, C);
    k_fin_out<<<gND, BLK, 0, stream>>>(C, dis, c31_b, fc21_w, fc21_b, out, 0);

    // conv32 head -> out[:,1]
    k_transform<<<gND, BLK, 0, stream>>>(A, c32_w, dis, B, C);
    k_scatter<<<gE32, BLK, 0, stream>>>(src, dst, B, C);
    k_fin_out<<<gND, BLK, 0, stream>>>(C, dis, c32_b, fc22_w, fc22_b, out, 1);
}

// Round 2
// 731.254 us; speedup vs baseline: 1.8132x; 1.8132x over previous
//
#include <hip/hip_runtime.h>

#define N_NODES 150000
#define N_EDGES 2400000
#define D 32
#define SCAN_BLK 256
#define NBLK_SCAN ((N_NODES + SCAN_BLK - 1) / SCAN_BLK)  // 586

// ---------- CSR build ----------
__global__ void k_zero_int(int* __restrict__ p, int n) {
    int i = blockIdx.x * blockDim.x + threadIdx.x;
    if (i < n) p[i] = 0;
}

__global__ void k_count(const int* __restrict__ dst, int* __restrict__ deg) {
    int e = blockIdx.x * blockDim.x + threadIdx.x;
    if (e < N_EDGES) atomicAdd(&deg[dst[e]], 1);
}

__global__ void k_scan1(const int* __restrict__ deg, int* __restrict__ row,
                        int* __restrict__ part) {
    __shared__ int s[SCAN_BLK];
    int t = threadIdx.x, i = blockIdx.x * SCAN_BLK + t;
    int v = (i < N_NODES) ? deg[i] : 0;
    s[t] = v;
    __syncthreads();
    for (int off = 1; off < SCAN_BLK; off <<= 1) {
        int add = (t >= off) ? s[t - off] : 0;
        __syncthreads();
        s[t] += add;
        __syncthreads();
    }
    if (i < N_NODES) row[i] = s[t] - v;  // exclusive within block
    if (t == SCAN_BLK - 1) part[blockIdx.x] = s[t];
}

__global__ void k_scan2(int* __restrict__ part) {
    __shared__ int s[1024];
    int t = threadIdx.x;
    int v = (t < NBLK_SCAN) ? part[t] : 0;
    s[t] = v;
    __syncthreads();
    for (int off = 1; off < 1024; off <<= 1) {
        int add = (t >= off) ? s[t - off] : 0;
        __syncthreads();
        s[t] += add;
        __syncthreads();
    }
    if (t < NBLK_SCAN) part[t] = s[t] - v;  // exclusive block offsets
}

__global__ void k_scan3(const int* __restrict__ deg, int* __restrict__ row,
                        const int* __restrict__ part, float* __restrict__ dis) {
    int i = blockIdx.x * blockDim.x + threadIdx.x;
    if (i < N_NODES) {
        row[i] += part[i >> 8];
        dis[i] = rsqrtf((float)deg[i] + 1.0f);  // +1 self-loop
    }
    if (i == 0) row[N_NODES] = N_EDGES;
}

__global__ void k_fill(const int* __restrict__ src, const int* __restrict__ dst,
                       const int* __restrict__ row, int* __restrict__ cur,
                       int* __restrict__ csr) {
    int e = blockIdx.x * blockDim.x + threadIdx.x;
    if (e >= N_EDGES) return;
    int d = dst[e];
    int p = atomicAdd(&cur[d], 1);
    csr[row[d] + p] = src[e];
}

// ---------- fc1: [N,2] @ [2,32] + b, relu ----------
__global__ void k_fc1(const float* __restrict__ x, const float* __restrict__ w,
                      const float* __restrict__ b, float* __restrict__ h) {
    int t = blockIdx.x * blockDim.x + threadIdx.x;
    if (t >= N_NODES * D) return;
    int i = t >> 5, f = t & 31;
    float v = fmaf(x[2 * i], w[f], fmaf(x[2 * i + 1], w[D + f], b[f]));
    h[t] = v > 0.f ? v : 0.f;
}

// ---------- hw[i][f] = dis[i] * sum_k h[i][k]*W[k][f] ----------
__global__ __launch_bounds__(256) void k_transform(const float* __restrict__ h,
                                                   const float* __restrict__ W,
                                                   const float* __restrict__ dis,
                                                   float* __restrict__ hw) {
    __shared__ float Ws[D * D];
    int lt = threadIdx.x;
    for (int k = lt; k < D * D; k += 256) Ws[k] = W[k];
    __syncthreads();
    int t = blockIdx.x * 256 + lt;
    int i = t >> 5, f = t & 31;
    if (i >= N_NODES) return;
    float hv = h[t];
    float a = 0.f;
#pragma unroll
    for (int k = 0; k < D; ++k) {
        float hk = __shfl(hv, k, 32);
        a = fmaf(hk, Ws[k * D + f], a);
    }
    hw[t] = a * dis[i];
}

// two weight matrices in one pass (heads); hw2 may alias h (each lane reads
// only its own h element into a register before any store)
__global__ __launch_bounds__(256) void k_transform2(const float* __restrict__ h,
                                                    const float* __restrict__ W1,
                                                    const float* __restrict__ W2,
                                                    const float* __restrict__ dis,
                                                    float* __restrict__ hw1,
                                                    float* __restrict__ hw2) {
    __shared__ float Ws1[D * D], Ws2[D * D];
    int lt = threadIdx.x;
    for (int k = lt; k < D * D; k += 256) { Ws1[k] = W1[k]; Ws2[k] = W2[k]; }
    __syncthreads();
    int t = blockIdx.x * 256 + lt;
    int i = t >> 5, f = t & 31;
    if (i >= N_NODES) return;
    float hv = h[t];
    float a1 = 0.f, a2 = 0.f;
#pragma unroll
    for (int k = 0; k < D; ++k) {
        float hk = __shfl(hv, k, 32);
        a1 = fmaf(hk, Ws1[k * D + f], a1);
        a2 = fmaf(hk, Ws2[k * D + f], a2);
    }
    float di = dis[i];
    hw1[t] = a1 * di;
    hw2[t] = a2 * di;
}

// ---------- gather + finalize: h[i] = relu(dis[i]*(hw[i] + sum_in hw[s]) + b) ----------
__global__ __launch_bounds__(256) void k_gather(const float* __restrict__ hw,
                                                const int* __restrict__ row,
                                                const int* __restrict__ csr,
                                                const float* __restrict__ dis,
                                                const float* __restrict__ b,
                                                float* __restrict__ h) {
    int t = blockIdx.x * 256 + threadIdx.x;
    int i = t >> 5, f = t & 31;
    if (i >= N_NODES) return;
    int rs = row[i], re = row[i + 1];
    float a = hw[t];  // self-loop term
    for (int j0 = rs; j0 < re; j0 += 32) {
        int rem = re - j0;
        int sidx = (f < rem) ? csr[j0 + f] : 0;
        int m = rem < 32 ? rem : 32;
        for (int j = 0; j < m; ++j) {
            int s = __shfl(sidx, j, 32);
            a += hw[s * D + f];
        }
    }
    float v = fmaf(a, dis[i], b[f]);
    h[t] = v > 0.f ? v : 0.f;
}

// combined head: both gathers + relu + 32->1 dots -> out[:,0], out[:,1]
__global__ __launch_bounds__(256) void k_gather_out2(
    const float* __restrict__ hw1, const float* __restrict__ hw2,
    const int* __restrict__ row, const int* __restrict__ csr,
    const float* __restrict__ dis, const float* __restrict__ b1,
    const float* __restrict__ b2, const float* __restrict__ fw1,
    const float* __restrict__ fb1, const float* __restrict__ fw2,
    const float* __restrict__ fb2, float* __restrict__ out) {
    int t = blockIdx.x * 256 + threadIdx.x;
    int i = t >> 5, f = t & 31;
    if (i >= N_NODES) return;
    int rs = row[i], re = row[i + 1];
    float a1 = hw1[t], a2 = hw2[t];
    for (int j0 = rs; j0 < re; j0 += 32) {
        int rem = re - j0;
        int sidx = (f < rem) ? csr[j0 + f] : 0;
        int m = rem < 32 ? rem : 32;
        for (int j = 0; j < m; ++j) {
            int s = __shfl(sidx, j, 32);
            a1 += hw1[s * D + f];
            a2 += hw2[s * D + f];
        }
    }
    float di = dis[i];
    float v1 = fmaf(a1, di, b1[f]);
    v1 = v1 > 0.f ? v1 : 0.f;
    v1 *= fw1[f];
    float v2 = fmaf(a2, di, b2[f]);
    v2 = v2 > 0.f ? v2 : 0.f;
    v2 *= fw2[f];
#pragma unroll
    for (int o = 16; o > 0; o >>= 1) {
        v1 += __shfl_down(v1, o, 32);
        v2 += __shfl_down(v2, o, 32);
    }
    if (f == 0) {
        out[i * 2] = v1 + fb1[0];
        out[i * 2 + 1] = v2 + fb2[0];
    }
}

extern "C" void kernel_launch(void* const* d_in, const int* in_sizes, int n_in,
                              void* d_out, int out_size, void* d_ws, size_t ws_size,
                              hipStream_t stream) {
    const float* x       = (const float*)d_in[0];
    const int*   eidx    = (const int*)d_in[1];
    const float* fc1_w   = (const float*)d_in[2];
    const float* fc1_b   = (const float*)d_in[3];
    const float* conv1_w = (const float*)d_in[4];
    const float* conv1_b = (const float*)d_in[5];
    const float* conv2_w = (const float*)d_in[6];
    const float* conv2_b = (const float*)d_in[7];
    const float* c31_w   = (const float*)d_in[8];
    const float* c31_b   = (const float*)d_in[9];
    const float* c32_w   = (const float*)d_in[10];
    const float* c32_b   = (const float*)d_in[11];
    const float* fc21_w  = (const float*)d_in[12];
    const float* fc21_b  = (const float*)d_in[13];
    const float* fc22_w  = (const float*)d_in[14];
    const float* fc22_b  = (const float*)d_in[15];
    float* out = (float*)d_out;

    const int* src = eidx;            // edge_index[0]
    const int* dst = eidx + N_EDGES;  // edge_index[1]

    float* dis = (float*)d_ws;                    // N
    float* A   = dis + N_NODES;                   // N*D (h / hw2)
    float* B   = A + (size_t)N_NODES * D;         // N*D (hw)
    int* ideg  = (int*)(B + (size_t)N_NODES * D); // N
    int* icur  = ideg + N_NODES;                  // N (contiguous after ideg)
    int* irow  = icur + N_NODES;                  // N+1
    int* ipart = irow + N_NODES + 1;              // 1024
    int* csr   = ipart + 1024;                    // E

    const int BLK = 256;
    const int gN   = (N_NODES + BLK - 1) / BLK;
    const int g2N  = (2 * N_NODES + BLK - 1) / BLK;
    const int gND  = (N_NODES * D + BLK - 1) / BLK;
    const int gE   = (N_EDGES + BLK - 1) / BLK;

    // ----- CSR build + normalization (once) -----
    k_zero_int<<<g2N, BLK, 0, stream>>>(ideg, 2 * N_NODES);  // ideg + icur
    k_count<<<gE, BLK, 0, stream>>>(dst, ideg);
    k_scan1<<<NBLK_SCAN, SCAN_BLK, 0, stream>>>(ideg, irow, ipart);
    k_scan2<<<1, 1024, 0, stream>>>(ipart);
    k_scan3<<<gN, BLK, 0, stream>>>(ideg, irow, ipart, dis);
    k_fill<<<gE, BLK, 0, stream>>>(src, dst, irow, icur, csr);

    // ----- network -----
    k_fc1<<<gND, BLK, 0, stream>>>(x, fc1_w, fc1_b, A);

    k_transform<<<gND, BLK, 0, stream>>>(A, conv1_w, dis, B);
    k_gather<<<gND, BLK, 0, stream>>>(B, irow, csr, dis, conv1_b, A);

    k_transform<<<gND, BLK, 0, stream>>>(A, conv2_w, dis, B);
    k_gather<<<gND, BLK, 0, stream>>>(B, irow, csr, dis, conv2_b, A);

    k_transform2<<<gND, BLK, 0, stream>>>(A, c31_w, c32_w, dis, B, A);
    k_gather_out2<<<gND, BLK, 0, stream>>>(B, A, irow, csr, dis, c31_b, c32_b,
                                           fc21_w, fc21_b, fc22_w, fc22_b, out);
}

// Round 3
// 486.380 us; speedup vs baseline: 2.7261x; 1.5035x over previous
//
#include <hip/hip_runtime.h>

#define N_NODES 150000
#define N_EDGES 2400000
#define D 32
#define SCAN_BLK 256
#define NBLK_SCAN ((N_NODES + SCAN_BLK - 1) / SCAN_BLK)  // 586

// ---------- CSR build ----------
__global__ void k_zero_int(int* __restrict__ p, int n) {
    int i = blockIdx.x * blockDim.x + threadIdx.x;
    if (i < n) p[i] = 0;
}

// count degrees AND record each edge's within-destination slot (no second atomic pass)
__global__ void k_count_pos(const int* __restrict__ dst, int* __restrict__ deg,
                            int* __restrict__ pos) {
    int e = blockIdx.x * blockDim.x + threadIdx.x;
    if (e < N_EDGES) pos[e] = atomicAdd(&deg[dst[e]], 1);
}

__global__ void k_scan1(const int* __restrict__ deg, int* __restrict__ row,
                        int* __restrict__ part) {
    __shared__ int s[SCAN_BLK];
    int t = threadIdx.x, i = blockIdx.x * SCAN_BLK + t;
    int v = (i < N_NODES) ? deg[i] : 0;
    s[t] = v;
    __syncthreads();
    for (int off = 1; off < SCAN_BLK; off <<= 1) {
        int add = (t >= off) ? s[t - off] : 0;
        __syncthreads();
        s[t] += add;
        __syncthreads();
    }
    if (i < N_NODES) row[i] = s[t] - v;  // exclusive within block
    if (t == SCAN_BLK - 1) part[blockIdx.x] = s[t];
}

__global__ void k_scan2(int* __restrict__ part) {
    __shared__ int s[1024];
    int t = threadIdx.x;
    int v = (t < NBLK_SCAN) ? part[t] : 0;
    s[t] = v;
    __syncthreads();
    for (int off = 1; off < 1024; off <<= 1) {
        int add = (t >= off) ? s[t - off] : 0;
        __syncthreads();
        s[t] += add;
        __syncthreads();
    }
    if (t < NBLK_SCAN) part[t] = s[t] - v;  // exclusive block offsets
}

__global__ void k_scan3(const int* __restrict__ deg, int* __restrict__ row,
                        const int* __restrict__ part, float* __restrict__ dis) {
    int i = blockIdx.x * blockDim.x + threadIdx.x;
    if (i < N_NODES) {
        row[i] += part[i >> 8];
        dis[i] = rsqrtf((float)deg[i] + 1.0f);  // +1 self-loop
    }
    if (i == 0) row[N_NODES] = N_EDGES;
}

// non-atomic fill using saved positions
__global__ void k_fill(const int* __restrict__ src, const int* __restrict__ dst,
                       const int* __restrict__ pos, const int* __restrict__ row,
                       int* __restrict__ csr) {
    int e = blockIdx.x * blockDim.x + threadIdx.x;
    if (e >= N_EDGES) return;
    csr[row[dst[e]] + pos[e]] = src[e];
}

// ---------- fc1: hsc0 = relu(x @ fc1_w + b) * dis ----------
__global__ void k_fc1(const float* __restrict__ x, const float* __restrict__ w,
                      const float* __restrict__ b, const float* __restrict__ dis,
                      float* __restrict__ hsc) {
    int t = blockIdx.x * blockDim.x + threadIdx.x;
    if (t >= N_NODES * D) return;
    int i = t >> 5, f = t & 31;
    float v = fmaf(x[2 * i], w[f], fmaf(x[2 * i + 1], w[D + f], b[f]));
    v = v > 0.f ? v : 0.f;
    hsc[t] = v * dis[i];
}

// ---------- fused layer: hout = relu( (dis_i * Σ_{s∈N(i)∪{i}} hsc[s]) @ W + b ) * dis_i ----------
__global__ __launch_bounds__(256) void k_layer(const float* __restrict__ hsc,
                                               const int* __restrict__ row,
                                               const int* __restrict__ csr,
                                               const float* __restrict__ dis,
                                               const float* __restrict__ W,
                                               const float* __restrict__ b,
                                               float* __restrict__ hout) {
    __shared__ float Ws[D * D];
    for (int k = threadIdx.x; k < D * D; k += 256) Ws[k] = W[k];
    __syncthreads();
    int t = blockIdx.x * 256 + threadIdx.x;
    int i = t >> 5, f = t & 31;
    if (i >= N_NODES) return;
    int rs = row[i], re = row[i + 1];
    float a = hsc[t];  // self-loop
    for (int j0 = rs; j0 < re; j0 += 32) {
        int rem = re - j0;
        int sidx = (f < rem) ? csr[j0 + f] : 0;
        int m = rem < 32 ? rem : 32;
        for (int j = 0; j < m; ++j) {
            int s = __shfl(sidx, j, 32);
            a += hsc[s * D + f];
        }
    }
    float di = dis[i];
    a *= di;  // aggregated feature f of node i
    float acc = 0.f;
#pragma unroll
    for (int k = 0; k < D; ++k) {
        float ak = __shfl(a, k, 32);
        acc = fmaf(ak, Ws[k * D + f], acc);
    }
    float v = acc + b[f];
    v = v > 0.f ? v : 0.f;
    hout[t] = v * di;
}

// ---------- heads: one gather, two transforms + relu + 32->1 dots -> out[:,0..1] ----------
__global__ __launch_bounds__(256) void k_heads(
    const float* __restrict__ hsc, const int* __restrict__ row,
    const int* __restrict__ csr, const float* __restrict__ dis,
    const float* __restrict__ W1, const float* __restrict__ b1,
    const float* __restrict__ W2, const float* __restrict__ b2,
    const float* __restrict__ fw1, const float* __restrict__ fb1,
    const float* __restrict__ fw2, const float* __restrict__ fb2,
    float* __restrict__ out) {
    __shared__ float Ws1[D * D], Ws2[D * D];
    for (int k = threadIdx.x; k < D * D; k += 256) { Ws1[k] = W1[k]; Ws2[k] = W2[k]; }
    __syncthreads();
    int t = blockIdx.x * 256 + threadIdx.x;
    int i = t >> 5, f = t & 31;
    if (i >= N_NODES) return;
    int rs = row[i], re = row[i + 1];
    float a = hsc[t];
    for (int j0 = rs; j0 < re; j0 += 32) {
        int rem = re - j0;
        int sidx = (f < rem) ? csr[j0 + f] : 0;
        int m = rem < 32 ? rem : 32;
        for (int j = 0; j < m; ++j) {
            int s = __shfl(sidx, j, 32);
            a += hsc[s * D + f];
        }
    }
    a *= dis[i];
    float a1 = 0.f, a2 = 0.f;
#pragma unroll
    for (int k = 0; k < D; ++k) {
        float ak = __shfl(a, k, 32);
        a1 = fmaf(ak, Ws1[k * D + f], a1);
        a2 = fmaf(ak, Ws2[k * D + f], a2);
    }
    float v1 = a1 + b1[f];
    v1 = (v1 > 0.f ? v1 : 0.f) * fw1[f];
    float v2 = a2 + b2[f];
    v2 = (v2 > 0.f ? v2 : 0.f) * fw2[f];
#pragma unroll
    for (int o = 16; o > 0; o >>= 1) {
        v1 += __shfl_down(v1, o, 32);
        v2 += __shfl_down(v2, o, 32);
    }
    if (f == 0) {
        out[i * 2] = v1 + fb1[0];
        out[i * 2 + 1] = v2 + fb2[0];
    }
}

extern "C" void kernel_launch(void* const* d_in, const int* in_sizes, int n_in,
                              void* d_out, int out_size, void* d_ws, size_t ws_size,
                              hipStream_t stream) {
    const float* x       = (const float*)d_in[0];
    const int*   eidx    = (const int*)d_in[1];
    const float* fc1_w   = (const float*)d_in[2];
    const float* fc1_b   = (const float*)d_in[3];
    const float* conv1_w = (const float*)d_in[4];
    const float* conv1_b = (const float*)d_in[5];
    const float* conv2_w = (const float*)d_in[6];
    const float* conv2_b = (const float*)d_in[7];
    const float* c31_w   = (const float*)d_in[8];
    const float* c31_b   = (const float*)d_in[9];
    const float* c32_w   = (const float*)d_in[10];
    const float* c32_b   = (const float*)d_in[11];
    const float* fc21_w  = (const float*)d_in[12];
    const float* fc21_b  = (const float*)d_in[13];
    const float* fc22_w  = (const float*)d_in[14];
    const float* fc22_b  = (const float*)d_in[15];
    float* out = (float*)d_out;

    const int* src = eidx;            // edge_index[0]
    const int* dst = eidx + N_EDGES;  // edge_index[1]

    float* dis = (float*)d_ws;                     // N
    float* HA  = dis + N_NODES;                    // N*D
    float* HB  = HA + (size_t)N_NODES * D;         // N*D
    int* ideg  = (int*)(HB + (size_t)N_NODES * D); // N
    int* irow  = ideg + N_NODES;                   // N+1
    int* ipart = irow + N_NODES + 1;               // 1024
    int* ipos  = ipart + 1024;                     // E
    int* csr   = ipos + N_EDGES;                   // E

    const int BLK = 256;
    const int gN  = (N_NODES + BLK - 1) / BLK;
    const int gND = (N_NODES * D + BLK - 1) / BLK;
    const int gE  = (N_EDGES + BLK - 1) / BLK;

    // ----- CSR build + normalization -----
    k_zero_int<<<gN, BLK, 0, stream>>>(ideg, N_NODES);
    k_count_pos<<<gE, BLK, 0, stream>>>(dst, ideg, ipos);
    k_scan1<<<NBLK_SCAN, SCAN_BLK, 0, stream>>>(ideg, irow, ipart);
    k_scan2<<<1, 1024, 0, stream>>>(ipart);
    k_scan3<<<gN, BLK, 0, stream>>>(ideg, irow, ipart, dis);
    k_fill<<<gE, BLK, 0, stream>>>(src, dst, ipos, irow, csr);

    // ----- network (aggregate-then-transform, fused per layer) -----
    k_fc1<<<gND, BLK, 0, stream>>>(x, fc1_w, fc1_b, dis, HA);
    k_layer<<<gND, BLK, 0, stream>>>(HA, irow, csr, dis, conv1_w, conv1_b, HB);
    k_layer<<<gND, BLK, 0, stream>>>(HB, irow, csr, dis, conv2_w, conv2_b, HA);
    k_heads<<<gND, BLK, 0, stream>>>(HA, irow, csr, dis, c31_w, c31_b, c32_w, c32_b,
                                     fc21_w, fc21_b, fc22_w, fc22_b, out);
}